// Round 18
// baseline (281.187 us; speedup 1.0000x reference)
//
#include <hip/hip_runtime.h>
#include <hip/hip_fp16.h>
#include <float.h>

#define NN 100000
#define NE 1600000
#define BK 32                     // nodes per bucket
#define NB 3125                   // NN / BK exactly
#define NSUB 8                    // classes (blockIdx % 8 of binning block)
#define SUBCAP 128                // capacity per (bucket,class): mean 64, +8 sd
#define BIN_BLOCKS 256
#define BIN_THREADS 1024
#define CHUNK 6250                // edges per binning block: 256 * 6250 = NE
#define CURPAD 16                 // ints per cursor (one 64B line each)

// order-preserving float<->uint encoding (monotonic, enc(x)>0 for all finite x)
__device__ __forceinline__ unsigned encf(float f) {
  unsigned u = __float_as_uint(f);
  return u ^ ((unsigned)((int)u >> 31) | 0x80000000u);
}
__device__ __forceinline__ float decf(unsigned u) {
  return __uint_as_float(u ^ ((u >> 31) ? 0x80000000u : 0xFFFFFFFFu));
}

__device__ __forceinline__ int ntload_i(const int* p) {
  return __builtin_nontemporal_load(p);
}
__device__ __forceinline__ float ntload_f(const float* p) {
  return __builtin_nontemporal_load(p);
}
__device__ __forceinline__ int2 ntload_i2(const int2* p) {
  unsigned long long v = __builtin_nontemporal_load((const unsigned long long*)p);
  int2 r; r.x = (int)(unsigned)(v & 0xFFFFFFFFull); r.y = (int)(unsigned)(v >> 32);
  return r;
}

// ---------------- bucket build ----------------

__global__ void k_zero_int(int* __restrict__ p, int n) {
  int i = blockIdx.x * blockDim.x + threadIdx.x;
  if (i < n) p[i] = 0;
}

// Two-pass block-aggregated binning (proven round-12/15 form).
__global__ __launch_bounds__(BIN_THREADS)
void k_bin(const int* __restrict__ src, const int* __restrict__ dst,
           const float* __restrict__ ew, int* __restrict__ gcur,
           int2* __restrict__ ebuf) {
  __shared__ int cnt[NB];     // pass1: histogram; pass2: running offset
  __shared__ int bofs[NB];    // reserved base per bucket
  int tid = threadIdx.x;
  int cls = blockIdx.x & 7;
  int e0 = blockIdx.x * CHUNK;
  for (int i = tid; i < NB; i += BIN_THREADS) cnt[i] = 0;
  __syncthreads();
  for (int k = tid; k < CHUNK; k += BIN_THREADS)
    atomicAdd(&cnt[ntload_i(dst + e0 + k) >> 5], 1);
  __syncthreads();
  for (int i = tid; i < NB; i += BIN_THREADS) {
    int c = cnt[i];
    bofs[i] = c ? atomicAdd(&gcur[((i << 3) | cls) * CURPAD], c) : 0;
  }
  __syncthreads();
  for (int i = tid; i < NB; i += BIN_THREADS) cnt[i] = 0;
  __syncthreads();
  for (int k = tid; k < CHUNK; k += BIN_THREADS) {
    int d = ntload_i(dst + e0 + k);
    int b = d >> 5;
    int pos = bofs[b] + atomicAdd(&cnt[b], 1);
    if (pos < SUBCAP)
      ebuf[(size_t)((b << 3) | cls) * SUBCAP + pos] =
          make_int2(ntload_i(src + e0 + k) | ((d & (BK - 1)) << 17),
                    __float_as_int(ntload_f(ew + e0 + k)));
  }
}

// ---------------- dense per-node GEMMs ----------------

// hp[n] = feat[n] @ W (16x16) + b, stored FP16; packs pv2 = (prv_diff, now)
__global__ void k_gemm_p16(const float* __restrict__ feat, const float* __restrict__ W,
                           const float* __restrict__ b, __half* __restrict__ out,
                           float2* __restrict__ pv2, int n) {
  __shared__ __align__(16) float sW[256];
  __shared__ float sb[16];
  for (int i = threadIdx.x; i < 256; i += blockDim.x) sW[i] = W[i];
  if (threadIdx.x < 16) sb[threadIdx.x] = b[threadIdx.x];
  __syncthreads();
  int node = blockIdx.x * blockDim.x + threadIdx.x;
  if (node >= n) return;
  float f[16];
  const float4* fr = (const float4*)(feat + (size_t)node * 16);
#pragma unroll
  for (int k = 0; k < 4; k++) {
    float4 t = fr[k];
    f[4 * k] = t.x; f[4 * k + 1] = t.y; f[4 * k + 2] = t.z; f[4 * k + 3] = t.w;
  }
  pv2[node] = make_float2(f[14], f[15]);
  uint2* op = (uint2*)out;
#pragma unroll 1
  for (int j = 0; j < 16; j += 4) {
    float4 acc = *(const float4*)(sb + j);
#pragma unroll
    for (int k = 0; k < 16; k++) {
      float4 w4 = *(const float4*)(sW + k * 16 + j);
      acc.x += f[k] * w4.x; acc.y += f[k] * w4.y;
      acc.z += f[k] * w4.z; acc.w += f[k] * w4.w;
    }
    union { __half2 h2[2]; uint2 u2; } cvt;
    cvt.h2[0] = __floats2half2_rn(acc.x, acc.y);
    cvt.h2[1] = __floats2half2_rn(acc.z, acc.w);
    op[((size_t)node * 16 + j) >> 2] = cvt.u2;
  }
}

// hp[n] = x[n] @ W (48x48) + b, stored FP16
__global__ void k_gemm_p48(const float* __restrict__ x, const float* __restrict__ W,
                           const float* __restrict__ b, __half* __restrict__ out, int n) {
  __shared__ __align__(16) float sW[48 * 48];
  __shared__ float sb[48];
  for (int i = threadIdx.x; i < 48 * 48; i += blockDim.x) sW[i] = W[i];
  if (threadIdx.x < 48) sb[threadIdx.x] = b[threadIdx.x];
  __syncthreads();
  int node = blockIdx.x * blockDim.x + threadIdx.x;
  if (node >= n) return;
  float f[48];
  const float4* fr = (const float4*)(x + (size_t)node * 48);
#pragma unroll
  for (int k = 0; k < 12; k++) {
    float4 t = fr[k];
    f[4 * k] = t.x; f[4 * k + 1] = t.y; f[4 * k + 2] = t.z; f[4 * k + 3] = t.w;
  }
  uint2* op = (uint2*)out;
#pragma unroll 1
  for (int j = 0; j < 48; j += 4) {
    float4 acc = *(const float4*)(sb + j);
#pragma unroll
    for (int k = 0; k < 48; k++) {
      float4 w4 = *(const float4*)(sW + k * 48 + j);
      acc.x += f[k] * w4.x; acc.y += f[k] * w4.y;
      acc.z += f[k] * w4.z; acc.w += f[k] * w4.w;
    }
    union { __half2 h2[2]; uint2 u2; } cvt;
    cvt.h2[0] = __floats2half2_rn(acc.x, acc.y);
    cvt.h2[1] = __floats2half2_rn(acc.z, acc.w);
    op[((size_t)node * 48 + j) >> 2] = cvt.u2;
  }
}

// ---------------- seg16 + fused gemm_n<16> + delta ----------------

__global__ __launch_bounds__(128)
void k_seg16n(const __half* __restrict__ hp, const float* __restrict__ feat,
              const float2* __restrict__ pv2, const int* __restrict__ gcur,
              const int2* __restrict__ ebuf, const float* __restrict__ Wn,
              const float* __restrict__ bn, float* __restrict__ xout,
              float* __restrict__ delta) {
  __shared__ unsigned smax[BK * 17];
  __shared__ float sdelta[BK];
  __shared__ int sn[NSUB];
  __shared__ __align__(16) float sW[32 * 48];   // Wn0 (6 KB)
  __shared__ float sb[48];
  int tid = threadIdx.x;
  for (int i = tid; i < BK * 17; i += 128) smax[i] = 0u;
  if (tid < BK) sdelta[tid] = 0.f;
  for (int i = tid; i < 32 * 48; i += 128) sW[i] = Wn[i];
  if (tid < 48) sb[tid] = bn[tid];
  int b = blockIdx.x;
  if (tid < NSUB) {
    int n = gcur[((b << 3) | tid) * CURPAD];
    sn[tid] = n > SUBCAP ? SUBCAP : n;
  }
  __syncthreads();
  int gg = tid >> 4;
  int f = tid & 15;
  const int2* eb = ebuf + (((size_t)b << 3) * SUBCAP);

  for (int win = 0; win < NSUB * SUBCAP; win += 64) {
    int cnt = sn[win >> 7];
    int wpos = win & (SUBCAP - 1);
    if (cnt <= wpos) continue;
    int2 r[8];
#pragma unroll
    for (int k = 0; k < 8; k++) r[k] = ntload_i2(eb + win + gg + 8 * k);
    __half h[8];
    float pv[8];
#pragma unroll
    for (int k = 0; k < 8; k++) {
      int s = (wpos + gg + 8 * k < cnt) ? (r[k].x & 0x1FFFF) : 0;
      h[k] = hp[(size_t)s * 16 + f];
      if (f == 0) pv[k] = pv2[s].x;
    }
#pragma unroll
    for (int k = 0; k < 8; k++) {
      if (wpos + gg + 8 * k < cnt) {
        int dl = (r[k].x >> 17) & (BK - 1);
        float w = __int_as_float(r[k].y);
        atomicMax(smax + dl * 17 + f, encf(__half2float(h[k]) * w));
        if (f == 0) atomicAdd(&sdelta[dl], pv[k] * w);
      }
    }
  }
  __syncthreads();
  size_t base = (size_t)b * BK;
  if (tid < BK) delta[base + tid] = sdelta[tid];
  // epilogue: 4 threads per node, 12 outputs each
  int node = tid >> 2;             // 0..31
  int j0 = (tid & 3) * 12;         // output column base
  float fv[32];
  const float4* fr = (const float4*)(feat + (base + node) * 16);
#pragma unroll
  for (int k = 0; k < 4; k++) {
    float4 t = fr[k];
    fv[4 * k] = t.x; fv[4 * k + 1] = t.y; fv[4 * k + 2] = t.z; fv[4 * k + 3] = t.w;
  }
#pragma unroll
  for (int k = 0; k < 16; k++) {
    unsigned v = smax[node * 17 + k];
    fv[16 + k] = v ? decf(v) : 0.0f;
  }
#pragma unroll
  for (int j = 0; j < 12; j++) {
    float acc = sb[j0 + j];
#pragma unroll
    for (int k = 0; k < 32; k++) acc += fv[k] * sW[k * 48 + j0 + j];
    xout[(base + node) * 48 + j0 + j] = fmaxf(acc, 0.f);
  }
}

// ---------------- seg48 + fused gemm_n48 (layer 1, in-place x update) ----------------
// Segmax identical to plain seg48 (LDS = 6.4 KB only -> full gather occupancy).
// Epilogue reads Wn1/bn1/x straight from global: all 3125 blocks hit the same
// 18 KB of weights -> pure L2 broadcast; no LDS tax on the gather phase.

__global__ __launch_bounds__(128)
void k_seg48n(const __half* __restrict__ hp, const int* __restrict__ gcur,
              const int2* __restrict__ ebuf, const float* __restrict__ Wn,
              const float* __restrict__ bn, float* __restrict__ x) {
  __shared__ unsigned smax[BK * 49];
  __shared__ int sn[NSUB];
  int tid = threadIdx.x;
  for (int i = tid; i < BK * 49; i += 128) smax[i] = 0u;
  int b = blockIdx.x;
  if (tid < NSUB) {
    int n = gcur[((b << 3) | tid) * CURPAD];
    sn[tid] = n > SUBCAP ? SUBCAP : n;
  }
  __syncthreads();
  int gg = tid >> 4;
  int f = tid & 15;
  const int2* eb = ebuf + (((size_t)b << 3) * SUBCAP);

  for (int win = 0; win < NSUB * SUBCAP; win += 64) {
    int cnt = sn[win >> 7];
    int wpos = win & (SUBCAP - 1);
    if (cnt <= wpos) continue;
    int2 r[8];
#pragma unroll
    for (int k = 0; k < 8; k++) r[k] = ntload_i2(eb + win + gg + 8 * k);
    __half h0[8], h1[8], h2[8];
#pragma unroll
    for (int k = 0; k < 8; k++) {
      int s = (wpos + gg + 8 * k < cnt) ? (r[k].x & 0x1FFFF) : 0;
      const __half* row = hp + (size_t)s * 48 + f;
      h0[k] = row[0]; h1[k] = row[16]; h2[k] = row[32];
    }
#pragma unroll
    for (int k = 0; k < 8; k++) {
      if (wpos + gg + 8 * k < cnt) {
        int dl = (r[k].x >> 17) & (BK - 1);
        float w = __int_as_float(r[k].y);
        unsigned* sm = smax + dl * 49 + f;
        atomicMax(sm,      encf(__half2float(h0[k]) * w));
        atomicMax(sm + 16, encf(__half2float(h1[k]) * w));
        atomicMax(sm + 32, encf(__half2float(h2[k]) * w));
      }
    }
  }
  __syncthreads();
  size_t base = (size_t)b * BK;
  // epilogue: 4 threads per node, 12 outputs each; weights + x from L2
  int node = tid >> 2;             // 0..31
  int j0 = (tid & 3) * 12;         // output column base
  const float* xr = x + (base + node) * 48;
  float acc[12];
#pragma unroll
  for (int j = 0; j < 12; j++) acc[j] = bn[j0 + j];
#pragma unroll 4
  for (int k = 0; k < 48; k++) {
    float xv = xr[k];
    const float4* w4 = (const float4*)(Wn + k * 48 + j0);
#pragma unroll
    for (int j = 0; j < 3; j++) {
      float4 t = w4[j];
      acc[4 * j]     += xv * t.x;
      acc[4 * j + 1] += xv * t.y;
      acc[4 * j + 2] += xv * t.z;
      acc[4 * j + 3] += xv * t.w;
    }
  }
#pragma unroll 4
  for (int k = 0; k < 48; k++) {
    unsigned v = smax[node * 49 + k];
    float nv = v ? decf(v) : 0.0f;
    const float4* w4 = (const float4*)(Wn + (48 + k) * 48 + j0);
#pragma unroll
    for (int j = 0; j < 3; j++) {
      float4 t = w4[j];
      acc[4 * j]     += nv * t.x;
      acc[4 * j + 1] += nv * t.y;
      acc[4 * j + 2] += nv * t.z;
      acc[4 * j + 3] += nv * t.w;
    }
  }
  __syncthreads();   // all x reads complete before in-place writes
#pragma unroll
  for (int j = 0; j < 12; j++)
    x[(base + node) * 48 + j0 + j] = fmaxf(acc[j], 0.f);
}

// ---------------- seg48 + fused final epilogue (layer 2) ----------------

__global__ __launch_bounds__(128)
void k_seg48f(const __half* __restrict__ hp, const int* __restrict__ gcur,
              const int2* __restrict__ ebuf, const float* __restrict__ x2,
              const float* __restrict__ Wn, const float* __restrict__ bn,
              const float2* __restrict__ pv2, const float* __restrict__ delta,
              float* __restrict__ out) {
  __shared__ unsigned smax[BK * 49];
  __shared__ int sn[NSUB];
  __shared__ __align__(16) float sW[96];
  __shared__ float sb;
  int tid = threadIdx.x;
  for (int i = tid; i < BK * 49; i += 128) smax[i] = 0u;
  if (tid < 96) sW[tid] = Wn[tid];
  if (tid == 0) sb = bn[0];
  int b = blockIdx.x;
  if (tid < NSUB) {
    int n = gcur[((b << 3) | tid) * CURPAD];
    sn[tid] = n > SUBCAP ? SUBCAP : n;
  }
  __syncthreads();
  int gg = tid >> 4;
  int f = tid & 15;
  const int2* eb = ebuf + (((size_t)b << 3) * SUBCAP);

  for (int win = 0; win < NSUB * SUBCAP; win += 64) {
    int cnt = sn[win >> 7];
    int wpos = win & (SUBCAP - 1);
    if (cnt <= wpos) continue;
    int2 r[8];
#pragma unroll
    for (int k = 0; k < 8; k++) r[k] = ntload_i2(eb + win + gg + 8 * k);
    __half h0[8], h1[8], h2[8];
#pragma unroll
    for (int k = 0; k < 8; k++) {
      int s = (wpos + gg + 8 * k < cnt) ? (r[k].x & 0x1FFFF) : 0;
      const __half* row = hp + (size_t)s * 48 + f;
      h0[k] = row[0]; h1[k] = row[16]; h2[k] = row[32];
    }
#pragma unroll
    for (int k = 0; k < 8; k++) {
      if (wpos + gg + 8 * k < cnt) {
        int dl = (r[k].x >> 17) & (BK - 1);
        float w = __int_as_float(r[k].y);
        unsigned* sm = smax + dl * 49 + f;
        atomicMax(sm,      encf(__half2float(h0[k]) * w));
        atomicMax(sm + 16, encf(__half2float(h1[k]) * w));
        atomicMax(sm + 32, encf(__half2float(h2[k]) * w));
      }
    }
  }
  __syncthreads();
  size_t base = (size_t)b * BK;
  // epilogue: 4 threads per node, 24 concat-terms each, shfl reduce
  int node = tid >> 2;
  int part = tid & 3;
  float acc = 0.f;
  if (part < 2) {
    const float* xr = x2 + (base + node) * 48 + part * 24;
#pragma unroll
    for (int k = 0; k < 24; k++) acc += xr[k] * sW[part * 24 + k];
  } else {
    int k0 = (part - 2) * 24;
#pragma unroll
    for (int k = 0; k < 24; k++) {
      unsigned v = smax[node * 49 + k0 + k];
      float nv = v ? decf(v) : 0.0f;
      acc += nv * sW[48 + k0 + k];
    }
  }
  acc += __shfl_xor(acc, 1, 64);
  acc += __shfl_xor(acc, 2, 64);
  if (part == 0) {
    float h = fmaxf(acc + sb, 0.f);
    float2 pn = pv2[base + node];
    float ub = fminf(fmaxf(pn.y + delta[base + node], 0.f), 1.f);
    out[base + node] = fminf(pn.y + h, ub);
  }
}

// ---------------- launch ----------------

extern "C" void kernel_launch(void* const* d_in, const int* in_sizes, int n_in,
                              void* d_out, int out_size, void* d_ws, size_t ws_size,
                              hipStream_t stream) {
  const float* features = (const float*)d_in[0];
  const float* ew = (const float*)d_in[1];
  const int* src = (const int*)d_in[2];
  const int* dst = (const int*)d_in[3];
  const float* Wp0 = (const float*)d_in[4];  const float* bp0 = (const float*)d_in[5];
  const float* Wn0 = (const float*)d_in[6];  const float* bn0 = (const float*)d_in[7];
  const float* Wp1 = (const float*)d_in[8];  const float* bp1 = (const float*)d_in[9];
  const float* Wn1 = (const float*)d_in[10]; const float* bn1 = (const float*)d_in[11];
  const float* Wp2 = (const float*)d_in[12]; const float* bp2 = (const float*)d_in[13];
  const float* Wn2 = (const float*)d_in[14]; const float* bn2 = (const float*)d_in[15];
  float* out = (float*)d_out;

  // workspace carve-up (~57 MB)
  char* base = (char*)d_ws;
  size_t off = 0;
  auto take = [&](size_t bytes) -> void* {
    void* p = base + off;
    off += (bytes + 255) & ~(size_t)255;
    return p;
  };
  __half* H     = (__half*)take((size_t)NN * 48 * 2);            // hp (fp16)
  float*  X1    = (float*)take((size_t)NN * 48 * 4);             // activations
  int*    gcur  = (int*)take((size_t)NB * NSUB * CURPAD * 4);    // 1.6 MB padded
  int2*   ebuf  = (int2*)take((size_t)NB * NSUB * SUBCAP * 8);   // 25.6 MB
  float*  delta = (float*)take((size_t)NN * 4);
  float2* pv2   = (float2*)take((size_t)NN * 8);
  (void)ws_size; (void)in_sizes; (void)n_in; (void)out_size;

  const int B = 256;
  int nbN = (NN + B - 1) / B;
  int nCur = NB * NSUB * CURPAD;

  // bucket build (reused by all 3 layers + delta)
  k_zero_int<<<(nCur + B - 1) / B, B, 0, stream>>>(gcur, nCur);
  k_bin<<<BIN_BLOCKS, BIN_THREADS, 0, stream>>>(src, dst, ew, gcur, ebuf);

  // layer 0: 16 -> 48 (segmax + delta + gemm_n<16> fused)
  k_gemm_p16<<<nbN, B, 0, stream>>>(features, Wp0, bp0, H, pv2, NN);
  k_seg16n<<<NB, 128, 0, stream>>>(H, features, pv2, gcur, ebuf, Wn0, bn0, X1, delta);

  // layer 1: 48 -> 48 (segmax + gemm_n48 fused, weights via L2 broadcast)
  k_gemm_p48<<<nbN, B, 0, stream>>>(X1, Wp1, bp1, H, NN);
  k_seg48n<<<NB, 128, 0, stream>>>(H, gcur, ebuf, Wn1, bn1, X1);

  // layer 2: 48 -> 1 (segmax + final epilogue fused)
  k_gemm_p48<<<nbN, B, 0, stream>>>(X1, Wp2, bp2, H, NN);
  k_seg48f<<<NB, 128, 0, stream>>>(H, gcur, ebuf, X1, Wn2, bn2, pv2, delta, out);
}

// Round 19
// 250.819 us; speedup vs baseline: 1.1211x; 1.1211x over previous
//
#include <hip/hip_runtime.h>
#include <hip/hip_fp16.h>
#include <float.h>

#define NN 100000
#define NE 1600000
#define BK 32                     // nodes per bucket
#define NB 3125                   // NN / BK exactly
#define NSUB 8                    // classes (blockIdx % 8 of binning block)
#define SUBCAP 128                // capacity per (bucket,class): mean 64, +8 sd
#define BIN_BLOCKS 256
#define CHUNK 6250                // edges per binning block: 256 * 6250 = NE
#define EPT 7                     // ceil(CHUNK / 1024) staged edges per thread
#define CURPAD 16                 // ints per cursor (one 64B line each)

// order-preserving float<->uint encoding (monotonic, enc(x)>0 for all finite x)
__device__ __forceinline__ unsigned encf(float f) {
  unsigned u = __float_as_uint(f);
  return u ^ ((unsigned)((int)u >> 31) | 0x80000000u);
}
__device__ __forceinline__ float decf(unsigned u) {
  return __uint_as_float(u ^ ((u >> 31) ? 0x80000000u : 0xFFFFFFFFu));
}

__device__ __forceinline__ int ntload_i(const int* p) {
  return __builtin_nontemporal_load(p);
}
__device__ __forceinline__ float ntload_f(const float* p) {
  return __builtin_nontemporal_load(p);
}
__device__ __forceinline__ int2 ntload_i2(const int2* p) {
  unsigned long long v = __builtin_nontemporal_load((const unsigned long long*)p);
  int2 r; r.x = (int)(unsigned)(v & 0xFFFFFFFFull); r.y = (int)(unsigned)(v >> 32);
  return r;
}

// ---------------- utility ----------------

__global__ void k_zero_int(int* __restrict__ p, int n) {
  int i = blockIdx.x * blockDim.x + threadIdx.x;
  if (i < n) p[i] = 0;
}

// ---------------- fused bucket build + gemm_p16 ----------------
// Blocks [0, BIN_BLOCKS): two-pass block-aggregated binning with REGISTER
// staging — the chunk's src/dst/ew are loaded ONCE into registers (21
// independent loads in flight at kernel entry), then histogram / reserve /
// scatter all run from registers (no second global read pass).
// Blocks [BIN_BLOCKS, ...): gemm_p16 (independent work, hides under bin).

__global__ __launch_bounds__(1024)
void k_binp16(const int* __restrict__ src, const int* __restrict__ dst,
              const float* __restrict__ ew, int* __restrict__ gcur,
              int2* __restrict__ ebuf, const float* __restrict__ feat,
              const float* __restrict__ W, const float* __restrict__ b,
              __half* __restrict__ hp, float2* __restrict__ pv2) {
  __shared__ int smem[2 * NB];          // bin: cnt+bofs (25 KB); p16: weights
  int tid = threadIdx.x;
  if (blockIdx.x < BIN_BLOCKS) {
    int* cnt = smem;
    int* bofs = smem + NB;
    int cls = blockIdx.x & 7;
    int e0 = blockIdx.x * CHUNK;
    // stage chunk into registers; clamped garbage never used (guards below)
    int rd[EPT], rs[EPT]; float rw[EPT];
#pragma unroll
    for (int k = 0; k < EPT; k++) {
      int idx = k * 1024 + tid;
      int g = e0 + (idx < CHUNK ? idx : CHUNK - 1);
      rd[k] = ntload_i(dst + g);
      rs[k] = ntload_i(src + g);
      rw[k] = ntload_f(ew + g);
    }
    for (int i = tid; i < NB; i += 1024) cnt[i] = 0;
    __syncthreads();
#pragma unroll
    for (int k = 0; k < EPT; k++)
      if (k * 1024 + tid < CHUNK) atomicAdd(&cnt[rd[k] >> 5], 1);
    __syncthreads();
    for (int i = tid; i < NB; i += 1024) {
      int c = cnt[i];
      bofs[i] = c ? atomicAdd(&gcur[((i << 3) | cls) * CURPAD], c) : 0;
    }
    __syncthreads();
    for (int i = tid; i < NB; i += 1024) cnt[i] = 0;
    __syncthreads();
#pragma unroll
    for (int k = 0; k < EPT; k++) {
      if (k * 1024 + tid < CHUNK) {
        int d = rd[k];
        int bb = d >> 5;
        int pos = bofs[bb] + atomicAdd(&cnt[bb], 1);
        if (pos < SUBCAP)
          ebuf[(size_t)((bb << 3) | cls) * SUBCAP + pos] =
              make_int2(rs[k] | ((d & (BK - 1)) << 17), __float_as_int(rw[k]));
      }
    }
  } else {
    // ---- gemm_p16: hp = feat @ Wp0 + bp0 (fp16), pv2 = (prv_diff, now) ----
    float* sW = (float*)smem;            // 256 floats
    float* sb = (float*)smem + 256;      // 16 floats
    if (tid < 256) sW[tid] = W[tid];
    if (tid < 16) sb[tid] = b[tid];
    __syncthreads();
    int node = (blockIdx.x - BIN_BLOCKS) * 1024 + tid;
    if (node >= NN) return;
    float f[16];
    const float4* fr = (const float4*)(feat + (size_t)node * 16);
#pragma unroll
    for (int k = 0; k < 4; k++) {
      float4 t = fr[k];
      f[4 * k] = t.x; f[4 * k + 1] = t.y; f[4 * k + 2] = t.z; f[4 * k + 3] = t.w;
    }
    pv2[node] = make_float2(f[14], f[15]);
    uint2* op = (uint2*)hp;
#pragma unroll 1
    for (int j = 0; j < 16; j += 4) {
      float4 acc = *(const float4*)(sb + j);
#pragma unroll
      for (int k = 0; k < 16; k++) {
        float4 w4 = *(const float4*)(sW + k * 16 + j);
        acc.x += f[k] * w4.x; acc.y += f[k] * w4.y;
        acc.z += f[k] * w4.z; acc.w += f[k] * w4.w;
      }
      union { __half2 h2[2]; uint2 u2; } cvt;
      cvt.h2[0] = __floats2half2_rn(acc.x, acc.y);
      cvt.h2[1] = __floats2half2_rn(acc.z, acc.w);
      op[((size_t)node * 16 + j) >> 2] = cvt.u2;
    }
  }
}

// ---------------- dense per-node GEMMs ----------------

// hp[n] = x[n] @ W (48x48) + b, stored FP16
__global__ void k_gemm_p48(const float* __restrict__ x, const float* __restrict__ W,
                           const float* __restrict__ b, __half* __restrict__ out, int n) {
  __shared__ __align__(16) float sW[48 * 48];
  __shared__ float sb[48];
  for (int i = threadIdx.x; i < 48 * 48; i += blockDim.x) sW[i] = W[i];
  if (threadIdx.x < 48) sb[threadIdx.x] = b[threadIdx.x];
  __syncthreads();
  int node = blockIdx.x * blockDim.x + threadIdx.x;
  if (node >= n) return;
  float f[48];
  const float4* fr = (const float4*)(x + (size_t)node * 48);
#pragma unroll
  for (int k = 0; k < 12; k++) {
    float4 t = fr[k];
    f[4 * k] = t.x; f[4 * k + 1] = t.y; f[4 * k + 2] = t.z; f[4 * k + 3] = t.w;
  }
  uint2* op = (uint2*)out;
#pragma unroll 1
  for (int j = 0; j < 48; j += 4) {
    float4 acc = *(const float4*)(sb + j);
#pragma unroll
    for (int k = 0; k < 48; k++) {
      float4 w4 = *(const float4*)(sW + k * 48 + j);
      acc.x += f[k] * w4.x; acc.y += f[k] * w4.y;
      acc.z += f[k] * w4.z; acc.w += f[k] * w4.w;
    }
    union { __half2 h2[2]; uint2 u2; } cvt;
    cvt.h2[0] = __floats2half2_rn(acc.x, acc.y);
    cvt.h2[1] = __floats2half2_rn(acc.z, acc.w);
    op[((size_t)node * 48 + j) >> 2] = cvt.u2;
  }
}

// out[n] = relu(concat(feat[n], neigh[n]) @ W (96 x 48) + b); in-place safe
__global__ void k_gemm_n48(const float* __restrict__ feat, const float* __restrict__ neigh,
                           const float* __restrict__ W, const float* __restrict__ b,
                           float* __restrict__ out, int n) {
  __shared__ __align__(16) float sW[96 * 48];
  __shared__ float sb[48];
  for (int i = threadIdx.x; i < 96 * 48; i += blockDim.x) sW[i] = W[i];
  if (threadIdx.x < 48) sb[threadIdx.x] = b[threadIdx.x];
  __syncthreads();
  int node = blockIdx.x * blockDim.x + threadIdx.x;
  if (node >= n) return;
  float f[96];
  const float4* fr = (const float4*)(feat + (size_t)node * 48);
#pragma unroll
  for (int k = 0; k < 12; k++) {
    float4 t = fr[k];
    f[4 * k] = t.x; f[4 * k + 1] = t.y; f[4 * k + 2] = t.z; f[4 * k + 3] = t.w;
  }
  const float4* nr = (const float4*)(neigh + (size_t)node * 48);
#pragma unroll
  for (int k = 0; k < 12; k++) {
    float4 t = nr[k];
    f[48 + 4 * k] = t.x; f[48 + 4 * k + 1] = t.y;
    f[48 + 4 * k + 2] = t.z; f[48 + 4 * k + 3] = t.w;
  }
  float4* op = (float4*)(out + (size_t)node * 48);
#pragma unroll 1
  for (int j = 0; j < 48; j += 4) {
    float4 acc = *(const float4*)(sb + j);
#pragma unroll
    for (int k = 0; k < 96; k++) {
      float4 w4 = *(const float4*)(sW + k * 48 + j);
      acc.x += f[k] * w4.x; acc.y += f[k] * w4.y;
      acc.z += f[k] * w4.z; acc.w += f[k] * w4.w;
    }
    acc.x = fmaxf(acc.x, 0.f); acc.y = fmaxf(acc.y, 0.f);
    acc.z = fmaxf(acc.z, 0.f); acc.w = fmaxf(acc.w, 0.f);
    op[j / 4] = acc;
  }
}

// ---------------- seg16 + fused gemm_n<16> + delta ----------------

__global__ __launch_bounds__(128)
void k_seg16n(const __half* __restrict__ hp, const float* __restrict__ feat,
              const float2* __restrict__ pv2, const int* __restrict__ gcur,
              const int2* __restrict__ ebuf, const float* __restrict__ Wn,
              const float* __restrict__ bn, float* __restrict__ xout,
              float* __restrict__ delta) {
  __shared__ unsigned smax[BK * 17];
  __shared__ float sdelta[BK];
  __shared__ int sn[NSUB];
  __shared__ __align__(16) float sW[32 * 48];   // Wn0 (6 KB)
  __shared__ float sb[48];
  int tid = threadIdx.x;
  for (int i = tid; i < BK * 17; i += 128) smax[i] = 0u;
  if (tid < BK) sdelta[tid] = 0.f;
  for (int i = tid; i < 32 * 48; i += 128) sW[i] = Wn[i];
  if (tid < 48) sb[tid] = bn[tid];
  int b = blockIdx.x;
  if (tid < NSUB) {
    int n = gcur[((b << 3) | tid) * CURPAD];
    sn[tid] = n > SUBCAP ? SUBCAP : n;
  }
  __syncthreads();
  int gg = tid >> 4;
  int f = tid & 15;
  const int2* eb = ebuf + (((size_t)b << 3) * SUBCAP);

  for (int win = 0; win < NSUB * SUBCAP; win += 64) {
    int cnt = sn[win >> 7];
    int wpos = win & (SUBCAP - 1);
    if (cnt <= wpos) continue;
    int2 r[8];
#pragma unroll
    for (int k = 0; k < 8; k++) r[k] = ntload_i2(eb + win + gg + 8 * k);
    __half h[8];
    float pv[8];
#pragma unroll
    for (int k = 0; k < 8; k++) {
      int s = (wpos + gg + 8 * k < cnt) ? (r[k].x & 0x1FFFF) : 0;
      h[k] = hp[(size_t)s * 16 + f];
      if (f == 0) pv[k] = pv2[s].x;
    }
#pragma unroll
    for (int k = 0; k < 8; k++) {
      if (wpos + gg + 8 * k < cnt) {
        int dl = (r[k].x >> 17) & (BK - 1);
        float w = __int_as_float(r[k].y);
        atomicMax(smax + dl * 17 + f, encf(__half2float(h[k]) * w));
        if (f == 0) atomicAdd(&sdelta[dl], pv[k] * w);
      }
    }
  }
  __syncthreads();
  size_t base = (size_t)b * BK;
  if (tid < BK) delta[base + tid] = sdelta[tid];
  // epilogue: 4 threads per node, 12 outputs each
  int node = tid >> 2;             // 0..31
  int j0 = (tid & 3) * 12;         // output column base
  float fv[32];
  const float4* fr = (const float4*)(feat + (base + node) * 16);
#pragma unroll
  for (int k = 0; k < 4; k++) {
    float4 t = fr[k];
    fv[4 * k] = t.x; fv[4 * k + 1] = t.y; fv[4 * k + 2] = t.z; fv[4 * k + 3] = t.w;
  }
#pragma unroll
  for (int k = 0; k < 16; k++) {
    unsigned v = smax[node * 17 + k];
    fv[16 + k] = v ? decf(v) : 0.0f;
  }
#pragma unroll
  for (int j = 0; j < 12; j++) {
    float acc = sb[j0 + j];
#pragma unroll
    for (int k = 0; k < 32; k++) acc += fv[k] * sW[k * 48 + j0 + j];
    xout[(base + node) * 48 + j0 + j] = fmaxf(acc, 0.f);
  }
}

// ---------------- plain seg48 (layer 1; neigh to global) ----------------

__global__ __launch_bounds__(128)
void k_seg48(const __half* __restrict__ hp, const int* __restrict__ gcur,
             const int2* __restrict__ ebuf, float* __restrict__ neigh) {
  __shared__ unsigned smax[BK * 49];
  __shared__ int sn[NSUB];
  int tid = threadIdx.x;
  for (int i = tid; i < BK * 49; i += 128) smax[i] = 0u;
  int b = blockIdx.x;
  if (tid < NSUB) {
    int n = gcur[((b << 3) | tid) * CURPAD];
    sn[tid] = n > SUBCAP ? SUBCAP : n;
  }
  __syncthreads();
  int gg = tid >> 4;
  int f = tid & 15;
  const int2* eb = ebuf + (((size_t)b << 3) * SUBCAP);

  for (int win = 0; win < NSUB * SUBCAP; win += 64) {
    int cnt = sn[win >> 7];
    int wpos = win & (SUBCAP - 1);
    if (cnt <= wpos) continue;
    int2 r[8];
#pragma unroll
    for (int k = 0; k < 8; k++) r[k] = ntload_i2(eb + win + gg + 8 * k);
    __half h0[8], h1[8], h2[8];
#pragma unroll
    for (int k = 0; k < 8; k++) {
      int s = (wpos + gg + 8 * k < cnt) ? (r[k].x & 0x1FFFF) : 0;
      const __half* row = hp + (size_t)s * 48 + f;
      h0[k] = row[0]; h1[k] = row[16]; h2[k] = row[32];
    }
#pragma unroll
    for (int k = 0; k < 8; k++) {
      if (wpos + gg + 8 * k < cnt) {
        int dl = (r[k].x >> 17) & (BK - 1);
        float w = __int_as_float(r[k].y);
        unsigned* sm = smax + dl * 49 + f;
        atomicMax(sm,      encf(__half2float(h0[k]) * w));
        atomicMax(sm + 16, encf(__half2float(h1[k]) * w));
        atomicMax(sm + 32, encf(__half2float(h2[k]) * w));
      }
    }
  }
  __syncthreads();
  size_t base = (size_t)b * BK;
  for (int i = tid; i < BK * 48; i += 128) {
    int node = i / 48, ff = i - node * 48;
    unsigned v = smax[node * 49 + ff];
    neigh[base * 48 + i] = v ? decf(v) : 0.0f;
  }
}

// ---------------- seg48 + fused final epilogue (layer 2) ----------------

__global__ __launch_bounds__(128)
void k_seg48f(const __half* __restrict__ hp, const int* __restrict__ gcur,
              const int2* __restrict__ ebuf, const float* __restrict__ x2,
              const float* __restrict__ Wn, const float* __restrict__ bn,
              const float2* __restrict__ pv2, const float* __restrict__ delta,
              float* __restrict__ out) {
  __shared__ unsigned smax[BK * 49];
  __shared__ int sn[NSUB];
  __shared__ __align__(16) float sW[96];
  __shared__ float sb;
  int tid = threadIdx.x;
  for (int i = tid; i < BK * 49; i += 128) smax[i] = 0u;
  if (tid < 96) sW[tid] = Wn[tid];
  if (tid == 0) sb = bn[0];
  int b = blockIdx.x;
  if (tid < NSUB) {
    int n = gcur[((b << 3) | tid) * CURPAD];
    sn[tid] = n > SUBCAP ? SUBCAP : n;
  }
  __syncthreads();
  int gg = tid >> 4;
  int f = tid & 15;
  const int2* eb = ebuf + (((size_t)b << 3) * SUBCAP);

  for (int win = 0; win < NSUB * SUBCAP; win += 64) {
    int cnt = sn[win >> 7];
    int wpos = win & (SUBCAP - 1);
    if (cnt <= wpos) continue;
    int2 r[8];
#pragma unroll
    for (int k = 0; k < 8; k++) r[k] = ntload_i2(eb + win + gg + 8 * k);
    __half h0[8], h1[8], h2[8];
#pragma unroll
    for (int k = 0; k < 8; k++) {
      int s = (wpos + gg + 8 * k < cnt) ? (r[k].x & 0x1FFFF) : 0;
      const __half* row = hp + (size_t)s * 48 + f;
      h0[k] = row[0]; h1[k] = row[16]; h2[k] = row[32];
    }
#pragma unroll
    for (int k = 0; k < 8; k++) {
      if (wpos + gg + 8 * k < cnt) {
        int dl = (r[k].x >> 17) & (BK - 1);
        float w = __int_as_float(r[k].y);
        unsigned* sm = smax + dl * 49 + f;
        atomicMax(sm,      encf(__half2float(h0[k]) * w));
        atomicMax(sm + 16, encf(__half2float(h1[k]) * w));
        atomicMax(sm + 32, encf(__half2float(h2[k]) * w));
      }
    }
  }
  __syncthreads();
  size_t base = (size_t)b * BK;
  // epilogue: 4 threads per node, 24 concat-terms each, shfl reduce
  int node = tid >> 2;
  int part = tid & 3;
  float acc = 0.f;
  if (part < 2) {
    const float* xr = x2 + (base + node) * 48 + part * 24;
#pragma unroll
    for (int k = 0; k < 24; k++) acc += xr[k] * sW[part * 24 + k];
  } else {
    int k0 = (part - 2) * 24;
#pragma unroll
    for (int k = 0; k < 24; k++) {
      unsigned v = smax[node * 49 + k0 + k];
      float nv = v ? decf(v) : 0.0f;
      acc += nv * sW[48 + k0 + k];
    }
  }
  acc += __shfl_xor(acc, 1, 64);
  acc += __shfl_xor(acc, 2, 64);
  if (part == 0) {
    float h = fmaxf(acc + sb, 0.f);
    float2 pn = pv2[base + node];
    float ub = fminf(fmaxf(pn.y + delta[base + node], 0.f), 1.f);
    out[base + node] = fminf(pn.y + h, ub);
  }
}

// ---------------- launch ----------------

extern "C" void kernel_launch(void* const* d_in, const int* in_sizes, int n_in,
                              void* d_out, int out_size, void* d_ws, size_t ws_size,
                              hipStream_t stream) {
  const float* features = (const float*)d_in[0];
  const float* ew = (const float*)d_in[1];
  const int* src = (const int*)d_in[2];
  const int* dst = (const int*)d_in[3];
  const float* Wp0 = (const float*)d_in[4];  const float* bp0 = (const float*)d_in[5];
  const float* Wn0 = (const float*)d_in[6];  const float* bn0 = (const float*)d_in[7];
  const float* Wp1 = (const float*)d_in[8];  const float* bp1 = (const float*)d_in[9];
  const float* Wn1 = (const float*)d_in[10]; const float* bn1 = (const float*)d_in[11];
  const float* Wp2 = (const float*)d_in[12]; const float* bp2 = (const float*)d_in[13];
  const float* Wn2 = (const float*)d_in[14]; const float* bn2 = (const float*)d_in[15];
  float* out = (float*)d_out;

  // workspace carve-up (~76 MB)
  char* base = (char*)d_ws;
  size_t off = 0;
  auto take = [&](size_t bytes) -> void* {
    void* p = base + off;
    off += (bytes + 255) & ~(size_t)255;
    return p;
  };
  __half* H     = (__half*)take((size_t)NN * 48 * 2);            // hp (fp16)
  float*  A     = (float*)take((size_t)NN * 48 * 4);             // neigh (layer 1)
  float*  X1    = (float*)take((size_t)NN * 48 * 4);             // activations
  int*    gcur  = (int*)take((size_t)NB * NSUB * CURPAD * 4);    // 1.6 MB padded
  int2*   ebuf  = (int2*)take((size_t)NB * NSUB * SUBCAP * 8);   // 25.6 MB
  float*  delta = (float*)take((size_t)NN * 4);
  float2* pv2   = (float2*)take((size_t)NN * 8);
  (void)ws_size; (void)in_sizes; (void)n_in; (void)out_size;

  const int B = 256;
  int nbN = (NN + B - 1) / B;
  int nCur = NB * NSUB * CURPAD;
  int p16Blocks = (NN + 1023) / 1024;            // 98

  // bucket build + gemm_p16 in one launch (independent work)
  k_zero_int<<<(nCur + B - 1) / B, B, 0, stream>>>(gcur, nCur);
  k_binp16<<<BIN_BLOCKS + p16Blocks, 1024, 0, stream>>>(
      src, dst, ew, gcur, ebuf, features, Wp0, bp0, H, pv2);

  // layer 0: 16 -> 48 (segmax + delta + gemm_n<16> fused)
  k_seg16n<<<NB, 128, 0, stream>>>(H, features, pv2, gcur, ebuf, Wn0, bn0, X1, delta);

  // layer 1: 48 -> 48 (split form — both fusion variants measured slower)
  k_gemm_p48<<<nbN, B, 0, stream>>>(X1, Wp1, bp1, H, NN);
  k_seg48<<<NB, 128, 0, stream>>>(H, gcur, ebuf, A);
  k_gemm_n48<<<nbN, B, 0, stream>>>(X1, A, Wn1, bn1, X1, NN);   // in-place

  // layer 2: 48 -> 1 (segmax + final epilogue fused)
  k_gemm_p48<<<nbN, B, 0, stream>>>(X1, Wp2, bp2, H, NN);
  k_seg48f<<<NB, 128, 0, stream>>>(H, gcur, ebuf, X1, Wn2, bn2, pv2, delta, out);
}

// Round 20
// 234.431 us; speedup vs baseline: 1.1994x; 1.0699x over previous
//
#include <hip/hip_runtime.h>
#include <hip/hip_fp16.h>
#include <float.h>

#define NN 100000
#define NE 1600000
#define BK 32                     // nodes per bucket
#define NB 3125                   // NN / BK exactly
#define NSUB 8                    // classes (blockIdx % 8 of binning block)
#define SUBCAP 128                // capacity per (bucket,class): mean 64, +8 sd
#define BIN_BLOCKS 256
#define CHUNK 6250                // edges per binning block: 256 * 6250 = NE
#define EPT 7                     // ceil(CHUNK / 1024) staged edges per thread
#define CURPAD 16                 // ints per cursor (one 64B line each)

// order-preserving float<->uint encoding (monotonic, enc(x)>0 for all finite x)
__device__ __forceinline__ unsigned encf(float f) {
  unsigned u = __float_as_uint(f);
  return u ^ ((unsigned)((int)u >> 31) | 0x80000000u);
}
__device__ __forceinline__ float decf(unsigned u) {
  return __uint_as_float(u ^ ((u >> 31) ? 0x80000000u : 0xFFFFFFFFu));
}

__device__ __forceinline__ int ntload_i(const int* p) {
  return __builtin_nontemporal_load(p);
}
__device__ __forceinline__ float ntload_f(const float* p) {
  return __builtin_nontemporal_load(p);
}
__device__ __forceinline__ int2 ntload_i2(const int2* p) {
  unsigned long long v = __builtin_nontemporal_load((const unsigned long long*)p);
  int2 r; r.x = (int)(unsigned)(v & 0xFFFFFFFFull); r.y = (int)(unsigned)(v >> 32);
  return r;
}

// ---------------- utility ----------------

__global__ void k_zero_int(int* __restrict__ p, int n) {
  int i = blockIdx.x * blockDim.x + threadIdx.x;
  if (i < n) p[i] = 0;
}

// ---------------- fused bucket build + gemm_p16 ----------------

__global__ __launch_bounds__(1024)
void k_binp16(const int* __restrict__ src, const int* __restrict__ dst,
              const float* __restrict__ ew, int* __restrict__ gcur,
              int2* __restrict__ ebuf, const float* __restrict__ feat,
              const float* __restrict__ W, const float* __restrict__ b,
              __half* __restrict__ hp, float2* __restrict__ pv2) {
  __shared__ int smem[2 * NB];          // bin: cnt+bofs (25 KB); p16: weights
  int tid = threadIdx.x;
  if (blockIdx.x < BIN_BLOCKS) {
    int* cnt = smem;
    int* bofs = smem + NB;
    int cls = blockIdx.x & 7;
    int e0 = blockIdx.x * CHUNK;
    // stage chunk into registers; clamped garbage never used (guards below)
    int rd[EPT], rs[EPT]; float rw[EPT];
#pragma unroll
    for (int k = 0; k < EPT; k++) {
      int idx = k * 1024 + tid;
      int g = e0 + (idx < CHUNK ? idx : CHUNK - 1);
      rd[k] = ntload_i(dst + g);
      rs[k] = ntload_i(src + g);
      rw[k] = ntload_f(ew + g);
    }
    for (int i = tid; i < NB; i += 1024) cnt[i] = 0;
    __syncthreads();
#pragma unroll
    for (int k = 0; k < EPT; k++)
      if (k * 1024 + tid < CHUNK) atomicAdd(&cnt[rd[k] >> 5], 1);
    __syncthreads();
    for (int i = tid; i < NB; i += 1024) {
      int c = cnt[i];
      bofs[i] = c ? atomicAdd(&gcur[((i << 3) | cls) * CURPAD], c) : 0;
    }
    __syncthreads();
    for (int i = tid; i < NB; i += 1024) cnt[i] = 0;
    __syncthreads();
#pragma unroll
    for (int k = 0; k < EPT; k++) {
      if (k * 1024 + tid < CHUNK) {
        int d = rd[k];
        int bb = d >> 5;
        int pos = bofs[bb] + atomicAdd(&cnt[bb], 1);
        if (pos < SUBCAP)
          ebuf[(size_t)((bb << 3) | cls) * SUBCAP + pos] =
              make_int2(rs[k] | ((d & (BK - 1)) << 17), __float_as_int(rw[k]));
      }
    }
  } else {
    // ---- gemm_p16: hp = feat @ Wp0 + bp0 (fp16), pv2 = (prv_diff, now) ----
    float* sW = (float*)smem;            // 256 floats
    float* sb = (float*)smem + 256;      // 16 floats
    if (tid < 256) sW[tid] = W[tid];
    if (tid < 16) sb[tid] = b[tid];
    __syncthreads();
    int node = (blockIdx.x - BIN_BLOCKS) * 1024 + tid;
    if (node >= NN) return;
    float f[16];
    const float4* fr = (const float4*)(feat + (size_t)node * 16);
#pragma unroll
    for (int k = 0; k < 4; k++) {
      float4 t = fr[k];
      f[4 * k] = t.x; f[4 * k + 1] = t.y; f[4 * k + 2] = t.z; f[4 * k + 3] = t.w;
    }
    pv2[node] = make_float2(f[14], f[15]);
    uint2* op = (uint2*)hp;
#pragma unroll 1
    for (int j = 0; j < 16; j += 4) {
      float4 acc = *(const float4*)(sb + j);
#pragma unroll
      for (int k = 0; k < 16; k++) {
        float4 w4 = *(const float4*)(sW + k * 16 + j);
        acc.x += f[k] * w4.x; acc.y += f[k] * w4.y;
        acc.z += f[k] * w4.z; acc.w += f[k] * w4.w;
      }
      union { __half2 h2[2]; uint2 u2; } cvt;
      cvt.h2[0] = __floats2half2_rn(acc.x, acc.y);
      cvt.h2[1] = __floats2half2_rn(acc.z, acc.w);
      op[((size_t)node * 16 + j) >> 2] = cvt.u2;
    }
  }
}

// ---------------- dense per-node GEMMs ----------------

// hp[n] = x[n] @ W (48x48) + b, stored FP16
__global__ void k_gemm_p48(const float* __restrict__ x, const float* __restrict__ W,
                           const float* __restrict__ b, __half* __restrict__ out, int n) {
  __shared__ __align__(16) float sW[48 * 48];
  __shared__ float sb[48];
  for (int i = threadIdx.x; i < 48 * 48; i += blockDim.x) sW[i] = W[i];
  if (threadIdx.x < 48) sb[threadIdx.x] = b[threadIdx.x];
  __syncthreads();
  int node = blockIdx.x * blockDim.x + threadIdx.x;
  if (node >= n) return;
  float f[48];
  const float4* fr = (const float4*)(x + (size_t)node * 48);
#pragma unroll
  for (int k = 0; k < 12; k++) {
    float4 t = fr[k];
    f[4 * k] = t.x; f[4 * k + 1] = t.y; f[4 * k + 2] = t.z; f[4 * k + 3] = t.w;
  }
  uint2* op = (uint2*)out;
#pragma unroll 1
  for (int j = 0; j < 48; j += 4) {
    float4 acc = *(const float4*)(sb + j);
#pragma unroll
    for (int k = 0; k < 48; k++) {
      float4 w4 = *(const float4*)(sW + k * 48 + j);
      acc.x += f[k] * w4.x; acc.y += f[k] * w4.y;
      acc.z += f[k] * w4.z; acc.w += f[k] * w4.w;
    }
    union { __half2 h2[2]; uint2 u2; } cvt;
    cvt.h2[0] = __floats2half2_rn(acc.x, acc.y);
    cvt.h2[1] = __floats2half2_rn(acc.z, acc.w);
    op[((size_t)node * 48 + j) >> 2] = cvt.u2;
  }
}

// out[n] = relu(concat(feat[n], neigh[n]) @ W (96 x 48) + b); in-place safe
__global__ void k_gemm_n48(const float* __restrict__ feat, const float* __restrict__ neigh,
                           const float* __restrict__ W, const float* __restrict__ b,
                           float* __restrict__ out, int n) {
  __shared__ __align__(16) float sW[96 * 48];
  __shared__ float sb[48];
  for (int i = threadIdx.x; i < 96 * 48; i += blockDim.x) sW[i] = W[i];
  if (threadIdx.x < 48) sb[threadIdx.x] = b[threadIdx.x];
  __syncthreads();
  int node = blockIdx.x * blockDim.x + threadIdx.x;
  if (node >= n) return;
  float f[96];
  const float4* fr = (const float4*)(feat + (size_t)node * 48);
#pragma unroll
  for (int k = 0; k < 12; k++) {
    float4 t = fr[k];
    f[4 * k] = t.x; f[4 * k + 1] = t.y; f[4 * k + 2] = t.z; f[4 * k + 3] = t.w;
  }
  const float4* nr = (const float4*)(neigh + (size_t)node * 48);
#pragma unroll
  for (int k = 0; k < 12; k++) {
    float4 t = nr[k];
    f[48 + 4 * k] = t.x; f[48 + 4 * k + 1] = t.y;
    f[48 + 4 * k + 2] = t.z; f[48 + 4 * k + 3] = t.w;
  }
  float4* op = (float4*)(out + (size_t)node * 48);
#pragma unroll 1
  for (int j = 0; j < 48; j += 4) {
    float4 acc = *(const float4*)(sb + j);
#pragma unroll
    for (int k = 0; k < 96; k++) {
      float4 w4 = *(const float4*)(sW + k * 48 + j);
      acc.x += f[k] * w4.x; acc.y += f[k] * w4.y;
      acc.z += f[k] * w4.z; acc.w += f[k] * w4.w;
    }
    acc.x = fmaxf(acc.x, 0.f); acc.y = fmaxf(acc.y, 0.f);
    acc.z = fmaxf(acc.z, 0.f); acc.w = fmaxf(acc.w, 0.f);
    op[j / 4] = acc;
  }
}

// ---------------- seg16 + fused gemm_n<16> + delta ----------------
// 8-lane groups x half2 gathers: 16 groups/block, 64 edge-chains per wave.

__global__ __launch_bounds__(128)
void k_seg16n(const __half* __restrict__ hp, const float* __restrict__ feat,
              const float2* __restrict__ pv2, const int* __restrict__ gcur,
              const int2* __restrict__ ebuf, const float* __restrict__ Wn,
              const float* __restrict__ bn, float* __restrict__ xout,
              float* __restrict__ delta) {
  __shared__ unsigned smax[BK * 17];
  __shared__ float sdelta[BK];
  __shared__ int sn[NSUB];
  __shared__ __align__(16) float sW[32 * 48];   // Wn0 (6 KB)
  __shared__ float sb[48];
  int tid = threadIdx.x;
  for (int i = tid; i < BK * 17; i += 128) smax[i] = 0u;
  if (tid < BK) sdelta[tid] = 0.f;
  for (int i = tid; i < 32 * 48; i += 128) sW[i] = Wn[i];
  if (tid < 48) sb[tid] = bn[tid];
  int b = blockIdx.x;
  if (tid < NSUB) {
    int n = gcur[((b << 3) | tid) * CURPAD];
    sn[tid] = n > SUBCAP ? SUBCAP : n;
  }
  __syncthreads();
  int g2 = tid >> 3;        // group id 0..15
  int l = tid & 7;          // lane in group (owns features 2l, 2l+1)
  const int2* eb = ebuf + (((size_t)b << 3) * SUBCAP);

  for (int win = 0; win < NSUB * SUBCAP; win += 128) {
    int cnt = sn[win >> 7];           // one class per 128-slot window
    if (cnt <= 0) continue;
    int2 r[8];
#pragma unroll
    for (int k = 0; k < 8; k++) r[k] = ntload_i2(eb + win + g2 + 16 * k);
    __half2 h[8];
    float pv[8];
#pragma unroll
    for (int k = 0; k < 8; k++) {
      int s = (g2 + 16 * k < cnt) ? (r[k].x & 0x1FFFF) : 0;
      h[k] = ((const __half2*)(hp + (size_t)s * 16))[l];
      if (l == 0) pv[k] = pv2[s].x;
    }
#pragma unroll
    for (int k = 0; k < 8; k++) {
      if (g2 + 16 * k < cnt) {
        int dl = (r[k].x >> 17) & (BK - 1);
        float w = __int_as_float(r[k].y);
        float2 v = __half22float2(h[k]);
        unsigned* sm = smax + dl * 17 + 2 * l;
        atomicMax(sm,     encf(v.x * w));
        atomicMax(sm + 1, encf(v.y * w));
        if (l == 0) atomicAdd(&sdelta[dl], pv[k] * w);
      }
    }
  }
  __syncthreads();
  size_t base = (size_t)b * BK;
  if (tid < BK) delta[base + tid] = sdelta[tid];
  // epilogue: 4 threads per node, 12 outputs each
  int node = tid >> 2;             // 0..31
  int j0 = (tid & 3) * 12;         // output column base
  float fv[32];
  const float4* fr = (const float4*)(feat + (base + node) * 16);
#pragma unroll
  for (int k = 0; k < 4; k++) {
    float4 t = fr[k];
    fv[4 * k] = t.x; fv[4 * k + 1] = t.y; fv[4 * k + 2] = t.z; fv[4 * k + 3] = t.w;
  }
#pragma unroll
  for (int k = 0; k < 16; k++) {
    unsigned v = smax[node * 17 + k];
    fv[16 + k] = v ? decf(v) : 0.0f;
  }
#pragma unroll
  for (int j = 0; j < 12; j++) {
    float acc = sb[j0 + j];
#pragma unroll
    for (int k = 0; k < 32; k++) acc += fv[k] * sW[k * 48 + j0 + j];
    xout[(base + node) * 48 + j0 + j] = fmaxf(acc, 0.f);
  }
}

// ---------------- plain seg48 (layer 1; neigh to global) ----------------
// 8-lane groups x 3 half2 gathers per edge.

__global__ __launch_bounds__(128)
void k_seg48(const __half* __restrict__ hp, const int* __restrict__ gcur,
             const int2* __restrict__ ebuf, float* __restrict__ neigh) {
  __shared__ unsigned smax[BK * 49];
  __shared__ int sn[NSUB];
  int tid = threadIdx.x;
  for (int i = tid; i < BK * 49; i += 128) smax[i] = 0u;
  int b = blockIdx.x;
  if (tid < NSUB) {
    int n = gcur[((b << 3) | tid) * CURPAD];
    sn[tid] = n > SUBCAP ? SUBCAP : n;
  }
  __syncthreads();
  int g2 = tid >> 3;
  int l = tid & 7;
  const int2* eb = ebuf + (((size_t)b << 3) * SUBCAP);

  for (int win = 0; win < NSUB * SUBCAP; win += 128) {
    int cnt = sn[win >> 7];
    if (cnt <= 0) continue;
    int2 r[8];
#pragma unroll
    for (int k = 0; k < 8; k++) r[k] = ntload_i2(eb + win + g2 + 16 * k);
    __half2 h0[8], h1[8], h2v[8];
#pragma unroll
    for (int k = 0; k < 8; k++) {
      int s = (g2 + 16 * k < cnt) ? (r[k].x & 0x1FFFF) : 0;
      const __half2* row = (const __half2*)(hp + (size_t)s * 48);
      h0[k] = row[l]; h1[k] = row[8 + l]; h2v[k] = row[16 + l];
    }
#pragma unroll
    for (int k = 0; k < 8; k++) {
      if (g2 + 16 * k < cnt) {
        int dl = (r[k].x >> 17) & (BK - 1);
        float w = __int_as_float(r[k].y);
        float2 v0 = __half22float2(h0[k]);
        float2 v1 = __half22float2(h1[k]);
        float2 v2 = __half22float2(h2v[k]);
        unsigned* sm = smax + dl * 49 + 2 * l;
        atomicMax(sm,      encf(v0.x * w));
        atomicMax(sm + 1,  encf(v0.y * w));
        atomicMax(sm + 16, encf(v1.x * w));
        atomicMax(sm + 17, encf(v1.y * w));
        atomicMax(sm + 32, encf(v2.x * w));
        atomicMax(sm + 33, encf(v2.y * w));
      }
    }
  }
  __syncthreads();
  size_t base = (size_t)b * BK;
  for (int i = tid; i < BK * 48; i += 128) {
    int node = i / 48, ff = i - node * 48;
    unsigned v = smax[node * 49 + ff];
    neigh[base * 48 + i] = v ? decf(v) : 0.0f;
  }
}

// ---------------- seg48 + fused final epilogue (layer 2) ----------------

__global__ __launch_bounds__(128)
void k_seg48f(const __half* __restrict__ hp, const int* __restrict__ gcur,
              const int2* __restrict__ ebuf, const float* __restrict__ x2,
              const float* __restrict__ Wn, const float* __restrict__ bn,
              const float2* __restrict__ pv2, const float* __restrict__ delta,
              float* __restrict__ out) {
  __shared__ unsigned smax[BK * 49];
  __shared__ int sn[NSUB];
  __shared__ __align__(16) float sW[96];
  __shared__ float sb;
  int tid = threadIdx.x;
  for (int i = tid; i < BK * 49; i += 128) smax[i] = 0u;
  if (tid < 96) sW[tid] = Wn[tid];
  if (tid == 0) sb = bn[0];
  int b = blockIdx.x;
  if (tid < NSUB) {
    int n = gcur[((b << 3) | tid) * CURPAD];
    sn[tid] = n > SUBCAP ? SUBCAP : n;
  }
  __syncthreads();
  int g2 = tid >> 3;
  int l = tid & 7;
  const int2* eb = ebuf + (((size_t)b << 3) * SUBCAP);

  for (int win = 0; win < NSUB * SUBCAP; win += 128) {
    int cnt = sn[win >> 7];
    if (cnt <= 0) continue;
    int2 r[8];
#pragma unroll
    for (int k = 0; k < 8; k++) r[k] = ntload_i2(eb + win + g2 + 16 * k);
    __half2 h0[8], h1[8], h2v[8];
#pragma unroll
    for (int k = 0; k < 8; k++) {
      int s = (g2 + 16 * k < cnt) ? (r[k].x & 0x1FFFF) : 0;
      const __half2* row = (const __half2*)(hp + (size_t)s * 48);
      h0[k] = row[l]; h1[k] = row[8 + l]; h2v[k] = row[16 + l];
    }
#pragma unroll
    for (int k = 0; k < 8; k++) {
      if (g2 + 16 * k < cnt) {
        int dl = (r[k].x >> 17) & (BK - 1);
        float w = __int_as_float(r[k].y);
        float2 v0 = __half22float2(h0[k]);
        float2 v1 = __half22float2(h1[k]);
        float2 v2 = __half22float2(h2v[k]);
        unsigned* sm = smax + dl * 49 + 2 * l;
        atomicMax(sm,      encf(v0.x * w));
        atomicMax(sm + 1,  encf(v0.y * w));
        atomicMax(sm + 16, encf(v1.x * w));
        atomicMax(sm + 17, encf(v1.y * w));
        atomicMax(sm + 32, encf(v2.x * w));
        atomicMax(sm + 33, encf(v2.y * w));
      }
    }
  }
  __syncthreads();
  size_t base = (size_t)b * BK;
  // epilogue: 4 threads per node, 24 concat-terms each, shfl reduce
  int node = tid >> 2;
  int part = tid & 3;
  float acc = 0.f;
  if (part < 2) {
    const float* xr = x2 + (base + node) * 48 + part * 24;
#pragma unroll
    for (int k = 0; k < 24; k++) acc += xr[k] * sW[part * 24 + k];
  } else {
    int k0 = (part - 2) * 24;
#pragma unroll
    for (int k = 0; k < 24; k++) {
      unsigned v = smax[node * 49 + k0 + k];
      float nv = v ? decf(v) : 0.0f;
      acc += nv * sW[48 + k0 + k];
    }
  }
  acc += __shfl_xor(acc, 1, 64);
  acc += __shfl_xor(acc, 2, 64);
  if (part == 0) {
    float h = fmaxf(acc + sb, 0.f);
    float2 pn = pv2[base + node];
    float ub = fminf(fmaxf(pn.y + delta[base + node], 0.f), 1.f);
    out[base + node] = fminf(pn.y + h, ub);
  }
}

// ---------------- launch ----------------

extern "C" void kernel_launch(void* const* d_in, const int* in_sizes, int n_in,
                              void* d_out, int out_size, void* d_ws, size_t ws_size,
                              hipStream_t stream) {
  const float* features = (const float*)d_in[0];
  const float* ew = (const float*)d_in[1];
  const int* src = (const int*)d_in[2];
  const int* dst = (const int*)d_in[3];
  const float* Wp0 = (const float*)d_in[4];  const float* bp0 = (const float*)d_in[5];
  const float* Wn0 = (const float*)d_in[6];  const float* bn0 = (const float*)d_in[7];
  const float* Wp1 = (const float*)d_in[8];  const float* bp1 = (const float*)d_in[9];
  const float* Wn1 = (const float*)d_in[10]; const float* bn1 = (const float*)d_in[11];
  const float* Wp2 = (const float*)d_in[12]; const float* bp2 = (const float*)d_in[13];
  const float* Wn2 = (const float*)d_in[14]; const float* bn2 = (const float*)d_in[15];
  float* out = (float*)d_out;

  // workspace carve-up (~76 MB)
  char* base = (char*)d_ws;
  size_t off = 0;
  auto take = [&](size_t bytes) -> void* {
    void* p = base + off;
    off += (bytes + 255) & ~(size_t)255;
    return p;
  };
  __half* H     = (__half*)take((size_t)NN * 48 * 2);            // hp (fp16)
  float*  A     = (float*)take((size_t)NN * 48 * 4);             // neigh (layer 1)
  float*  X1    = (float*)take((size_t)NN * 48 * 4);             // activations
  int*    gcur  = (int*)take((size_t)NB * NSUB * CURPAD * 4);    // 1.6 MB padded
  int2*   ebuf  = (int2*)take((size_t)NB * NSUB * SUBCAP * 8);   // 25.6 MB
  float*  delta = (float*)take((size_t)NN * 4);
  float2* pv2   = (float2*)take((size_t)NN * 8);
  (void)ws_size; (void)in_sizes; (void)n_in; (void)out_size;

  const int B = 256;
  int nbN = (NN + B - 1) / B;
  int nCur = NB * NSUB * CURPAD;
  int p16Blocks = (NN + 1023) / 1024;            // 98

  // bucket build + gemm_p16 in one launch (independent work)
  k_zero_int<<<(nCur + B - 1) / B, B, 0, stream>>>(gcur, nCur);
  k_binp16<<<BIN_BLOCKS + p16Blocks, 1024, 0, stream>>>(
      src, dst, ew, gcur, ebuf, features, Wp0, bp0, H, pv2);

  // layer 0: 16 -> 48 (segmax + delta + gemm_n<16> fused)
  k_seg16n<<<NB, 128, 0, stream>>>(H, features, pv2, gcur, ebuf, Wn0, bn0, X1, delta);

  // layer 1: 48 -> 48 (split form — fusion variants measured slower)
  k_gemm_p48<<<nbN, B, 0, stream>>>(X1, Wp1, bp1, H, NN);
  k_seg48<<<NB, 128, 0, stream>>>(H, gcur, ebuf, A);
  k_gemm_n48<<<nbN, B, 0, stream>>>(X1, A, Wn1, bn1, X1, NN);   // in-place

  // layer 2: 48 -> 1 (segmax + final epilogue fused)
  k_gemm_p48<<<nbN, B, 0, stream>>>(X1, Wp2, bp2, H, NN);
  k_seg48f<<<NB, 128, 0, stream>>>(H, gcur, ebuf, X1, Wn2, bn2, pv2, delta, out);
}